// Round 10
// baseline (921.086 us; speedup 1.0000x reference)
//
#include <hip/hip_runtime.h>
#include <hip/hip_bf16.h>

// G2-GCN fused pipeline for MI355X — round 10.
// vs round 9 (879us):
// (1) 2-rows-per-load gathers: wave splits into halves (lanes 0-31 row A,
//     32-63 row B); lane loads a feature PAIR (float2 fp32 / uint=2xbf16).
//     Halves gather instruction count (the measured pin is per-instruction
//     outstanding-miss slots: fp32 and bf16 rows gathered at the same row
//     rate). tau stays PER-FEATURE (r5's fatal bug was scalar tau).
// (2) non-temporal loads for all edge/csr streams (k_degrees, k_fill, and
//     csr index reads in gathers): streaming reads no longer evict dirty
//     CSR lines (k_fill WRITE_SIZE 62MB for 6.4MB payload) or hot rows.

#define N_NODES 50000
#define N_EDGES 800000
#define N_GRAPH 500
#define N_LAYERS 4
#define HDIM 64
#define DDIN 128
#define BN_EPS 1e-5f
#define NEPART 256
#define SC_CHUNK 2048
#define SC_NBLK ((N_NODES + SC_CHUNK - 1) / SC_CHUNK)  // 25
#define NPARTS 8
#define PRNG (N_NODES / NPARTS)  // 6250 exactly
#define FILL_BPP 56

typedef __hip_bfloat16 bf16;

__device__ __forceinline__ float bflo(unsigned int u) {
  return __uint_as_float(u << 16);
}
__device__ __forceinline__ float bfhi(unsigned int u) {
  return __uint_as_float(u & 0xffff0000u);
}
__device__ __forceinline__ unsigned short f2bf(float f) {
  bf16 h = __float2bfloat16(f);
  return *reinterpret_cast<unsigned short*>(&h);
}

// ---------------- CSR build ----------------

__global__ __launch_bounds__(256) void k_degrees(const int* __restrict__ ei,
                                                 int* __restrict__ deg_in,
                                                 int* __restrict__ deg_out) {
  int part = blockIdx.x & (NPARTS - 1);
  int slice = blockIdx.x >> 3;
  int nslice = gridDim.x >> 3;
  int lo = part * PRNG, hi = lo + PRNG;
  int stride = nslice * 256;
  for (int e = slice * 256 + threadIdx.x; e < N_EDGES; e += stride) {
    int s = __builtin_nontemporal_load(ei + e);
    int d = __builtin_nontemporal_load(ei + N_EDGES + e);
    if (s >= lo && s < hi) atomicAdd(&deg_out[s], 1);
    if (d >= lo && d < hi) atomicAdd(&deg_in[d], 1);
  }
}

__global__ __launch_bounds__(256) void k_scan1(const int* __restrict__ deg_in,
                                               const int* __restrict__ deg_out,
                                               int* __restrict__ rp_dst,
                                               int* __restrict__ rp_src,
                                               int* __restrict__ bsum) {
  int arr = blockIdx.y;
  const int* in = arr ? deg_out : deg_in;
  int* out = arr ? rp_src : rp_dst;
  int base = blockIdx.x * SC_CHUNK + threadIdx.x * 8;
  int v[8];
  int s = 0;
#pragma unroll
  for (int j = 0; j < 8; ++j) {
    int ii = base + j;
    v[j] = (ii < N_NODES) ? in[ii] : 0;
    s += v[j];
  }
  __shared__ int sh[256];
  sh[threadIdx.x] = s;
  __syncthreads();
  for (int off = 1; off < 256; off <<= 1) {
    int t = (threadIdx.x >= off) ? sh[threadIdx.x - off] : 0;
    __syncthreads();
    sh[threadIdx.x] += t;
    __syncthreads();
  }
  int run = sh[threadIdx.x] - s;
#pragma unroll
  for (int j = 0; j < 8; ++j) {
    int ii = base + j;
    if (ii < N_NODES) out[ii] = run;
    run += v[j];
  }
  if (threadIdx.x == 255) bsum[arr * SC_NBLK + blockIdx.x] = sh[255];
}

__global__ __launch_bounds__(64) void k_scan2(const int* __restrict__ bsum,
                                              int* __restrict__ boff,
                                              int* __restrict__ rp_dst,
                                              int* __restrict__ rp_src) {
  int lane = threadIdx.x;
  for (int a = 0; a < 2; ++a) {
    int v = (lane < SC_NBLK) ? bsum[a * SC_NBLK + lane] : 0;
    int incl = v;
    for (int off = 1; off < 64; off <<= 1) {
      int t = __shfl_up(incl, off);
      if (lane >= off) incl += t;
    }
    if (lane < SC_NBLK) boff[a * SC_NBLK + lane] = incl - v;
  }
  if (lane == 0) {
    rp_dst[N_NODES] = N_EDGES;
    rp_src[N_NODES] = N_EDGES;
  }
}

__global__ __launch_bounds__(256) void k_scan3(const int* __restrict__ boff,
                                               int* __restrict__ rp_dst,
                                               int* __restrict__ rp_src,
                                               int* __restrict__ cur_dst,
                                               int* __restrict__ cur_src,
                                               const int* __restrict__ deg_in,
                                               float* __restrict__ dinv) {
  int arr = blockIdx.y;
  int* rp = arr ? rp_src : rp_dst;
  int* cur = arr ? cur_src : cur_dst;
  int off = boff[arr * SC_NBLK + blockIdx.x];
  int base = blockIdx.x * SC_CHUNK + threadIdx.x * 8;
#pragma unroll
  for (int j = 0; j < 8; ++j) {
    int ii = base + j;
    if (ii < N_NODES) {
      int v = rp[ii] + off;
      rp[ii] = v;
      cur[ii] = v;
      if (arr == 0) dinv[ii] = rsqrtf((float)(deg_in[ii] + 1));  // + self loop
    }
  }
}

__global__ __launch_bounds__(256) void k_fill(const int* __restrict__ ei,
                                              int* __restrict__ cur_dst,
                                              int* __restrict__ cur_src,
                                              int* __restrict__ csr_dst,
                                              int* __restrict__ csr_src) {
  int part = blockIdx.x & (NPARTS - 1);
  int slice = blockIdx.x >> 3;
  int nslice = gridDim.x >> 3;
  int lo = part * PRNG, hi = lo + PRNG;
  int stride = nslice * 256;
  for (int e = slice * 256 + threadIdx.x; e < N_EDGES; e += stride) {
    int s = __builtin_nontemporal_load(ei + e);
    int d = __builtin_nontemporal_load(ei + N_EDGES + e);
    if (d >= lo && d < hi) {
      int q = atomicAdd(&cur_dst[d], 1);
      csr_dst[q] = s;
    }
    if (s >= lo && s < hi) {
      int q = atomicAdd(&cur_src[s], 1);
      csr_src[q] = d;
    }
  }
}

// ---------------- dense kernels ----------------

__global__ __launch_bounds__(256) void k_prelin(const float* __restrict__ x0,
                                                const float* __restrict__ W,
                                                const float* __restrict__ b,
                                                const float* __restrict__ dinv,
                                                float* __restrict__ x,
                                                float* __restrict__ xs) {
  __shared__ float Ws[DDIN * HDIM];  // 32 KB
  for (int t = threadIdx.x; t < DDIN * HDIM; t += 256) Ws[t] = W[t];
  __syncthreads();
  int wave = threadIdx.x >> 6, lane = threadIdx.x & 63;
  float bias = b[lane];
  int stride = gridDim.x * 4;
  for (int i = blockIdx.x * 4 + wave; i < N_NODES; i += stride) {
    const float* xr = x0 + (size_t)i * DDIN;
    float xl0 = xr[lane], xl1 = xr[64 + lane];
    float acc = bias;
#pragma unroll
    for (int k = 0; k < 64; ++k) acc = fmaf(__shfl(xl0, k), Ws[k * 64 + lane], acc);
#pragma unroll
    for (int k = 0; k < 64; ++k) acc = fmaf(__shfl(xl1, k), Ws[(64 + k) * 64 + lane], acc);
    float xv = fmaxf(acc, 0.f);
    size_t li = (size_t)i * HDIM + lane;
    x[li] = xv;
    xs[li] = xv * dinv[i];
  }
}

// ---------------- gathers: 2 rows per load instruction ----------------------
// Wave layout: half = lane>>5 (row selector within an edge pair),
// fl = lane&31 (feature-pair index: features 2*fl, 2*fl+1).

// aggb[i] = dinv[i] * (xs[i] + sum_in xs[s]);  xs rows gathered as float2.
__global__ __launch_bounds__(256) void k_agg(const float* __restrict__ xs,
                                             const int* __restrict__ rp,
                                             const int* __restrict__ csr,
                                             const float* __restrict__ dinv,
                                             float* __restrict__ aggb) {
  int i = (blockIdx.x * 256 + threadIdx.x) >> 6;
  int lane = threadIdx.x & 63;
  if (i >= N_NODES) return;
  int half = lane >> 5, fl = lane & 31;
  const float2* xs2 = (const float2*)xs;  // row stride = 32 float2
  int e0 = rp[i], e1 = rp[i + 1];
  float di = dinv[i];
  float2 a0 = make_float2(0.f, 0.f), a1 = a0, a2 = a0, a3 = a0;
  if (half == 0) a0 = xs2[(size_t)i * 32 + fl];  // self loop, counted once
  for (int base = e0; base < e1; base += 64) {
    int m = e1 - base;
    if (m > 64) m = 64;
    int idx = __builtin_nontemporal_load(csr + base + (lane < m ? lane : 0));
    int k = 0;
    for (; k + 16 <= m; k += 16) {
      int r0 = __shfl(idx, k + half),      r1 = __shfl(idx, k + 2 + half);
      int r2 = __shfl(idx, k + 4 + half),  r3 = __shfl(idx, k + 6 + half);
      int r4 = __shfl(idx, k + 8 + half),  r5 = __shfl(idx, k + 10 + half);
      int r6 = __shfl(idx, k + 12 + half), r7 = __shfl(idx, k + 14 + half);
      float2 v0 = xs2[(size_t)r0 * 32 + fl], v1 = xs2[(size_t)r1 * 32 + fl];
      float2 v2 = xs2[(size_t)r2 * 32 + fl], v3 = xs2[(size_t)r3 * 32 + fl];
      float2 v4 = xs2[(size_t)r4 * 32 + fl], v5 = xs2[(size_t)r5 * 32 + fl];
      float2 v6 = xs2[(size_t)r6 * 32 + fl], v7 = xs2[(size_t)r7 * 32 + fl];
      a0.x += v0.x; a0.y += v0.y; a1.x += v1.x; a1.y += v1.y;
      a2.x += v2.x; a2.y += v2.y; a3.x += v3.x; a3.y += v3.y;
      a0.x += v4.x; a0.y += v4.y; a1.x += v5.x; a1.y += v5.y;
      a2.x += v6.x; a2.y += v6.y; a3.x += v7.x; a3.y += v7.y;
    }
    for (; k < m; k += 2) {
      int kk = k + half;
      int r = __shfl(idx, kk < m ? kk : k);
      if (kk < m) {
        float2 v = xs2[(size_t)r * 32 + fl];
        a0.x += v.x;
        a0.y += v.y;
      }
    }
  }
  float2 a;
  a.x = (a0.x + a1.x) + (a2.x + a3.x);
  a.y = (a0.y + a1.y) + (a2.y + a3.y);
  a.x += __shfl_xor(a.x, 32);  // combine edge halves (features match across halves)
  a.y += __shfl_xor(a.y, 32);
  if (half == 0) {
    float2 r;
    r.x = a.x * di;
    r.y = a.y * di;
    ((float2*)aggb)[(size_t)i * 32 + fl] = r;
  }
}

// streaming dual GEMM (r8-verified): x_ fp32, Xch bf16.
__global__ __launch_bounds__(256) void k_gemm2(const float* __restrict__ agg,
                                               const float* __restrict__ W1,
                                               const float* __restrict__ W2,
                                               const float* __restrict__ b1,
                                               const float* __restrict__ b2,
                                               float* __restrict__ x_,
                                               bf16* __restrict__ Xch) {
  __shared__ float W1s[HDIM * HDIM], W2s[HDIM * HDIM];
  for (int t = threadIdx.x; t < HDIM * HDIM; t += 256) {
    W1s[t] = W1[t];
    W2s[t] = W2[t];
  }
  __syncthreads();
  int wave = threadIdx.x >> 6, lane = threadIdx.x & 63;
  float bb1 = b1[lane], bb2 = b2[lane];
  int stride = gridDim.x * 4;
  for (int i = blockIdx.x * 4 + wave; i < N_NODES; i += stride) {
    size_t li = (size_t)i * HDIM + lane;
    float xl = agg[li];
    float r1 = 0.f, r2 = 0.f;
#pragma unroll
    for (int k = 0; k < 64; ++k) {
      float xv = __shfl(xl, k);
      r1 = fmaf(xv, W1s[k * 64 + lane], r1);
      r2 = fmaf(xv, W2s[k * 64 + lane], r2);
    }
    x_[li] = fmaxf(r1 + bb1, 0.f);
    Xch[li] = __float2bfloat16(fmaxf(r2 + bb2, 0.f));
  }
}

// PER-FEATURE tau (reference: tau is [N,H]); bf16 rows gathered as uint pairs.
// x = (1-tau)*x + tau*x_ ; emit xh (bf16) and xs = x*dinv.
__global__ __launch_bounds__(256) void k_gate(const bf16* __restrict__ Xch,
                                              const float* __restrict__ x_,
                                              const int* __restrict__ rp,
                                              const int* __restrict__ csr,
                                              const float* __restrict__ dinv,
                                              float* __restrict__ x,
                                              bf16* __restrict__ xh,
                                              float* __restrict__ xs) {
  int i = (blockIdx.x * 256 + threadIdx.x) >> 6;
  int lane = threadIdx.x & 63;
  if (i >= N_NODES) return;
  int half = lane >> 5, fl = lane & 31;
  const unsigned int* X2 = (const unsigned int*)Xch;  // row stride = 32 uints
  int e0 = rp[i], e1 = rp[i + 1];
  unsigned int xiu = X2[(size_t)i * 32 + fl];
  float xiA = bflo(xiu), xiB = bfhi(xiu);
  // per-feature accumulators: sA for feature 2*fl, sB for 2*fl+1
  float sA0 = 0.f, sA1 = 0.f, sB0 = 0.f, sB1 = 0.f;
  for (int base = e0; base < e1; base += 64) {
    int m = e1 - base;
    if (m > 64) m = 64;
    int idx = __builtin_nontemporal_load(csr + base + (lane < m ? lane : 0));
    int k = 0;
    for (; k + 16 <= m; k += 16) {
      int r0 = __shfl(idx, k + half),      r1 = __shfl(idx, k + 2 + half);
      int r2 = __shfl(idx, k + 4 + half),  r3 = __shfl(idx, k + 6 + half);
      int r4 = __shfl(idx, k + 8 + half),  r5 = __shfl(idx, k + 10 + half);
      int r6 = __shfl(idx, k + 12 + half), r7 = __shfl(idx, k + 14 + half);
      unsigned int u0 = X2[(size_t)r0 * 32 + fl], u1 = X2[(size_t)r1 * 32 + fl];
      unsigned int u2 = X2[(size_t)r2 * 32 + fl], u3 = X2[(size_t)r3 * 32 + fl];
      unsigned int u4 = X2[(size_t)r4 * 32 + fl], u5 = X2[(size_t)r5 * 32 + fl];
      unsigned int u6 = X2[(size_t)r6 * 32 + fl], u7 = X2[(size_t)r7 * 32 + fl];
      float t;
      t = xiA - bflo(u0); sA0 = fmaf(t, t, sA0);
      t = xiB - bfhi(u0); sB0 = fmaf(t, t, sB0);
      t = xiA - bflo(u1); sA1 = fmaf(t, t, sA1);
      t = xiB - bfhi(u1); sB1 = fmaf(t, t, sB1);
      t = xiA - bflo(u2); sA0 = fmaf(t, t, sA0);
      t = xiB - bfhi(u2); sB0 = fmaf(t, t, sB0);
      t = xiA - bflo(u3); sA1 = fmaf(t, t, sA1);
      t = xiB - bfhi(u3); sB1 = fmaf(t, t, sB1);
      t = xiA - bflo(u4); sA0 = fmaf(t, t, sA0);
      t = xiB - bfhi(u4); sB0 = fmaf(t, t, sB0);
      t = xiA - bflo(u5); sA1 = fmaf(t, t, sA1);
      t = xiB - bfhi(u5); sB1 = fmaf(t, t, sB1);
      t = xiA - bflo(u6); sA0 = fmaf(t, t, sA0);
      t = xiB - bfhi(u6); sB0 = fmaf(t, t, sB0);
      t = xiA - bflo(u7); sA1 = fmaf(t, t, sA1);
      t = xiB - bfhi(u7); sB1 = fmaf(t, t, sB1);
    }
    for (; k < m; k += 2) {
      int kk = k + half;
      int r = __shfl(idx, kk < m ? kk : k);
      if (kk < m) {
        unsigned int u = X2[(size_t)r * 32 + fl];
        float t = xiA - bflo(u);
        sA0 = fmaf(t, t, sA0);
        t = xiB - bfhi(u);
        sB0 = fmaf(t, t, sB0);
      }
    }
  }
  float sA = sA0 + sA1, sB = sB0 + sB1;
  sA += __shfl_xor(sA, 32);  // combine edge halves per feature
  sB += __shfl_xor(sB, 32);
  int cnt = e1 - e0;
  float inv = 1.f / (float)(cnt > 0 ? cnt : 1);
  float tauA = tanhf(sA * inv);
  float tauB = tanhf(sB * inv);
  if (half == 0) {
    float di = dinv[i];
    size_t o = (size_t)i * 32 + fl;
    float2 xv = ((const float2*)x)[o];
    float2 xn_ = ((const float2*)x_)[o];
    float2 xn;
    xn.x = (1.f - tauA) * xv.x + tauA * xn_.x;
    xn.y = (1.f - tauB) * xv.y + tauB * xn_.y;
    ((float2*)x)[o] = xn;
    float2 xsv;
    xsv.x = xn.x * di;
    xsv.y = xn.y * di;
    ((float2*)xs)[o] = xsv;
    ((unsigned int*)xh)[o] =
        (unsigned int)f2bf(xn.x) | ((unsigned int)f2bf(xn.y) << 16);
  }
}

// energy partials (scalar total — full-wave reduce is correct here).
__global__ __launch_bounds__(256) void k_epool(const bf16* __restrict__ xh,
                                               const int* __restrict__ rp,
                                               const int* __restrict__ csr,
                                               float* __restrict__ epart) {
  int i = (blockIdx.x * 256 + threadIdx.x) >> 6;
  int lane = threadIdx.x & 63;
  if (i >= N_NODES) return;
  int half = lane >> 5, fl = lane & 31;
  const unsigned int* X2 = (const unsigned int*)xh;
  unsigned int xiu = X2[(size_t)i * 32 + fl];
  float xiA = bflo(xiu), xiB = bfhi(xiu);
  int e0 = rp[i], e1 = rp[i + 1];
  float a0 = 0.f, a1 = 0.f, a2 = 0.f, a3 = 0.f;
  for (int base = e0; base < e1; base += 64) {
    int m = e1 - base;
    if (m > 64) m = 64;
    int idx = __builtin_nontemporal_load(csr + base + (lane < m ? lane : 0));
    int k = 0;
    for (; k + 16 <= m; k += 16) {
      int r0 = __shfl(idx, k + half),      r1 = __shfl(idx, k + 2 + half);
      int r2 = __shfl(idx, k + 4 + half),  r3 = __shfl(idx, k + 6 + half);
      int r4 = __shfl(idx, k + 8 + half),  r5 = __shfl(idx, k + 10 + half);
      int r6 = __shfl(idx, k + 12 + half), r7 = __shfl(idx, k + 14 + half);
      unsigned int u0 = X2[(size_t)r0 * 32 + fl], u1 = X2[(size_t)r1 * 32 + fl];
      unsigned int u2 = X2[(size_t)r2 * 32 + fl], u3 = X2[(size_t)r3 * 32 + fl];
      unsigned int u4 = X2[(size_t)r4 * 32 + fl], u5 = X2[(size_t)r5 * 32 + fl];
      unsigned int u6 = X2[(size_t)r6 * 32 + fl], u7 = X2[(size_t)r7 * 32 + fl];
      float t;
      t = xiA - bflo(u0); a0 = fmaf(t, t, a0);
      t = xiB - bfhi(u0); a1 = fmaf(t, t, a1);
      t = xiA - bflo(u1); a2 = fmaf(t, t, a2);
      t = xiB - bfhi(u1); a3 = fmaf(t, t, a3);
      t = xiA - bflo(u2); a0 = fmaf(t, t, a0);
      t = xiB - bfhi(u2); a1 = fmaf(t, t, a1);
      t = xiA - bflo(u3); a2 = fmaf(t, t, a2);
      t = xiB - bfhi(u3); a3 = fmaf(t, t, a3);
      t = xiA - bflo(u4); a0 = fmaf(t, t, a0);
      t = xiB - bfhi(u4); a1 = fmaf(t, t, a1);
      t = xiA - bflo(u5); a2 = fmaf(t, t, a2);
      t = xiB - bfhi(u5); a3 = fmaf(t, t, a3);
      t = xiA - bflo(u6); a0 = fmaf(t, t, a0);
      t = xiB - bfhi(u6); a1 = fmaf(t, t, a1);
      t = xiA - bflo(u7); a2 = fmaf(t, t, a2);
      t = xiB - bfhi(u7); a3 = fmaf(t, t, a3);
    }
    for (; k < m; k += 2) {
      int kk = k + half;
      int r = __shfl(idx, kk < m ? kk : k);
      if (kk < m) {
        unsigned int u = X2[(size_t)r * 32 + fl];
        float t = xiA - bflo(u);
        a0 = fmaf(t, t, a0);
        t = xiB - bfhi(u);
        a1 = fmaf(t, t, a1);
      }
    }
  }
  float acc = (a0 + a1) + (a2 + a3);
  acc += __shfl_down(acc, 32);
  acc += __shfl_down(acc, 16);
  acc += __shfl_down(acc, 8);
  acc += __shfl_down(acc, 4);
  acc += __shfl_down(acc, 2);
  acc += __shfl_down(acc, 1);
  if (lane == 0) atomicAdd(&epart[i & (NEPART - 1)], acc);
}

__global__ __launch_bounds__(256) void k_esum(const float* __restrict__ epart,
                                              float* __restrict__ out_e) {
  __shared__ float sh[NEPART];
  int t = threadIdx.x;
  sh[t] = epart[t];
  __syncthreads();
  for (int off = NEPART / 2; off > 0; off >>= 1) {
    if (t < off) sh[t] += sh[t + off];
    __syncthreads();
  }
  if (t == 0) out_e[0] = 0.5f * sh[0];
}

// global add pool, no atomics (batch sorted): one block per graph.
__global__ __launch_bounds__(256) void k_pool2(const float* __restrict__ x,
                                               const int* __restrict__ batch,
                                               float* __restrict__ hpool) {
  int g = blockIdx.x;
  int a = 0, b = N_NODES;
  while (a < b) {
    int mid = (a + b) >> 1;
    if (batch[mid] < g) a = mid + 1; else b = mid;
  }
  int lo = a;
  b = N_NODES;
  while (a < b) {
    int mid = (a + b) >> 1;
    if (batch[mid] < g + 1) a = mid + 1; else b = mid;
  }
  int hi = a;
  int wave = threadIdx.x >> 6, lane = threadIdx.x & 63;
  float acc = 0.f;
  for (int i = lo + wave; i < hi; i += 4) acc += x[(size_t)i * HDIM + lane];
  __shared__ float sh[4][HDIM];
  sh[wave][lane] = acc;
  __syncthreads();
  if (wave == 0)
    hpool[g * HDIM + lane] = (sh[0][lane] + sh[1][lane]) + (sh[2][lane] + sh[3][lane]);
}

// ---------------- readout MLP (fused GEMM + BN + relu) ----------------------

__global__ __launch_bounds__(256) void k_mlpbn(const float* __restrict__ Hin,
                                               const float* __restrict__ W,
                                               const float* __restrict__ b,
                                               const float* __restrict__ g,
                                               const float* __restrict__ bb,
                                               float* __restrict__ Z) {
  int c = blockIdx.x;
  __shared__ float Wc[HDIM];
  __shared__ float red[256];
  if (threadIdx.x < HDIM) Wc[threadIdx.x] = W[threadIdx.x * HDIM + c];
  __syncthreads();
  int r0 = threadIdx.x, r1 = threadIdx.x + 256;
  float bc = b[c];
  float d0 = bc, d1 = bc;
  if (r0 < N_GRAPH) {
    const float* h = Hin + (size_t)r0 * HDIM;
#pragma unroll
    for (int k = 0; k < HDIM; ++k) d0 = fmaf(h[k], Wc[k], d0);
  }
  if (r1 < N_GRAPH) {
    const float* h = Hin + (size_t)r1 * HDIM;
#pragma unroll
    for (int k = 0; k < HDIM; ++k) d1 = fmaf(h[k], Wc[k], d1);
  }
  red[threadIdx.x] = (r0 < N_GRAPH ? d0 : 0.f) + (r1 < N_GRAPH ? d1 : 0.f);
  __syncthreads();
  for (int off = 128; off > 0; off >>= 1) {
    if (threadIdx.x < off) red[threadIdx.x] += red[threadIdx.x + off];
    __syncthreads();
  }
  float mean = red[0] / (float)N_GRAPH;
  __syncthreads();
  float t0 = (r0 < N_GRAPH) ? d0 - mean : 0.f;
  float t1 = (r1 < N_GRAPH) ? d1 - mean : 0.f;
  red[threadIdx.x] = t0 * t0 + t1 * t1;
  __syncthreads();
  for (int off = 128; off > 0; off >>= 1) {
    if (threadIdx.x < off) red[threadIdx.x] += red[threadIdx.x + off];
    __syncthreads();
  }
  float var = red[0] / (float)N_GRAPH;
  float scale = rsqrtf(var + BN_EPS) * g[c];
  float bias = bb[c];
  if (r0 < N_GRAPH) Z[(size_t)r0 * HDIM + c] = fmaxf(fmaf(t0, scale, bias), 0.f);
  if (r1 < N_GRAPH) Z[(size_t)r1 * HDIM + c] = fmaxf(fmaf(t1, scale, bias), 0.f);
}

__global__ __launch_bounds__(256) void k_final(const float* __restrict__ H,
                                               const float* __restrict__ w,
                                               const float* __restrict__ b,
                                               float* __restrict__ out) {
  int r = blockIdx.x * 256 + threadIdx.x;
  if (r >= N_GRAPH) return;
  float acc = b[0];
#pragma unroll
  for (int k = 0; k < 64; ++k) acc = fmaf(H[r * HDIM + k], w[k], acc);
  out[r] = acc;
  out[N_GRAPH + r] = acc;
}

// ---------------- launch ----------------

extern "C" void kernel_launch(void* const* d_in, const int* in_sizes, int n_in,
                              void* d_out, int out_size, void* d_ws, size_t ws_size,
                              hipStream_t stream) {
  (void)in_sizes; (void)n_in; (void)out_size; (void)ws_size;
  const float* x0    = (const float*)d_in[0];
  const int*   ei    = (const int*)d_in[1];
  const int*   batch = (const int*)d_in[2];
  const float* preW  = (const float*)d_in[3];
  const float* preb  = (const float*)d_in[4];
  const float* convW = (const float*)d_in[5];
  const float* convb = (const float*)d_in[6];
  const float* ggW   = (const float*)d_in[7];
  const float* ggb   = (const float*)d_in[8];
  const float* lin1W = (const float*)d_in[9];
  const float* lin1b = (const float*)d_in[10];
  const float* lin2W = (const float*)d_in[11];
  const float* lin2b = (const float*)d_in[12];
  const float* lin3W = (const float*)d_in[13];
  const float* lin3b = (const float*)d_in[14];
  const float* lin4W = (const float*)d_in[15];
  const float* lin4b = (const float*)d_in[16];
  const float* bng   = (const float*)d_in[17];
  const float* bnb   = (const float*)d_in[18];
  float* out = (float*)d_out;

  char* ws = (char*)d_ws;
  size_t off = 0;
  auto alloc = [&](size_t bytes) -> void* {
    off = (off + 255) & ~(size_t)255;
    void* p = ws + off;
    off += bytes;
    return p;
  };
  int* deg_in   = (int*)alloc(2ull * N_NODES * 4);  // deg_in, deg_out (memset)
  int* deg_out  = deg_in + N_NODES;
  int* rp_dst   = (int*)alloc((N_NODES + 1) * 4);
  int* rp_src   = (int*)alloc((N_NODES + 1) * 4);
  int* cur_dst  = (int*)alloc((N_NODES + 1) * 4);
  int* cur_src  = (int*)alloc((N_NODES + 1) * 4);
  int* bsum     = (int*)alloc(2 * SC_NBLK * 4);
  int* boff     = (int*)alloc(2 * SC_NBLK * 4);
  int* csr_dst  = (int*)alloc((size_t)N_EDGES * 4);
  int* csr_src  = (int*)alloc((size_t)N_EDGES * 4);
  float* dinv   = (float*)alloc(N_NODES * 4);
  float* x      = (float*)alloc((size_t)N_NODES * HDIM * 4);
  float* xs     = (float*)alloc((size_t)N_NODES * HDIM * 4);
  float* aggb   = (float*)alloc((size_t)N_NODES * HDIM * 4);
  float* x_     = (float*)alloc((size_t)N_NODES * HDIM * 4);
  bf16* Xch     = (bf16*)alloc((size_t)N_NODES * HDIM * 2);
  bf16* xh      = (bf16*)alloc((size_t)N_NODES * HDIM * 2);
  float* hpool  = (float*)alloc(N_GRAPH * HDIM * 4);
  float* epart  = (float*)alloc(NEPART * 4);
  float* mlpA   = (float*)alloc(N_GRAPH * HDIM * 4);
  float* mlpB   = (float*)alloc(N_GRAPH * HDIM * 4);

  hipMemsetAsync(deg_in, 0, 2ull * N_NODES * 4, stream);
  hipMemsetAsync(epart, 0, NEPART * 4, stream);

  k_degrees<<<NPARTS * FILL_BPP, 256, 0, stream>>>(ei, deg_in, deg_out);
  {
    dim3 g(SC_NBLK, 2);
    k_scan1<<<g, 256, 0, stream>>>(deg_in, deg_out, rp_dst, rp_src, bsum);
    k_scan2<<<1, 64, 0, stream>>>(bsum, boff, rp_dst, rp_src);
    k_scan3<<<g, 256, 0, stream>>>(boff, rp_dst, rp_src, cur_dst, cur_src, deg_in, dinv);
  }
  k_fill<<<NPARTS * FILL_BPP, 256, 0, stream>>>(ei, cur_dst, cur_src, csr_dst, csr_src);

  k_prelin<<<512, 256, 0, stream>>>(x0, preW, preb, dinv, x, xs);

  const int gnode = (N_NODES + 3) / 4;
  for (int l = 0; l < N_LAYERS; ++l) {
    k_agg<<<gnode, 256, 0, stream>>>(xs, rp_dst, csr_dst, dinv, aggb);
    k_gemm2<<<1024, 256, 0, stream>>>(aggb, convW + l * HDIM * HDIM, ggW + l * HDIM * HDIM,
                                      convb + l * HDIM, ggb + l * HDIM, x_, Xch);
    k_gate<<<gnode, 256, 0, stream>>>(Xch, x_, rp_src, csr_src, dinv, x, xh, xs);
  }

  k_epool<<<gnode, 256, 0, stream>>>(xh, rp_src, csr_src, epart);
  k_esum<<<1, NEPART, 0, stream>>>(epart, out + 2 * N_GRAPH);
  k_pool2<<<N_GRAPH, 256, 0, stream>>>(x, batch, hpool);

  k_mlpbn<<<HDIM, 256, 0, stream>>>(hpool, lin1W, lin1b, bng, bnb, mlpA);
  k_mlpbn<<<HDIM, 256, 0, stream>>>(mlpA, lin2W, lin2b, bng, bnb, mlpB);
  k_mlpbn<<<HDIM, 256, 0, stream>>>(mlpB, lin3W, lin3b, bng, bnb, mlpA);
  k_final<<<(N_GRAPH + 255) / 256, 256, 0, stream>>>(mlpA, lin4W, lin4b, out);
}

// Round 11
// 875.615 us; speedup vs baseline: 1.0519x; 1.0519x over previous
//
#include <hip/hip_runtime.h>
#include <hip/hip_bf16.h>

// G2-GCN fused pipeline for MI355X — round 11 = revert to round 8 (best: 871us).
// Rounds 9/10 tested three independent gather levers (dinv prescale + no-atomic
// pool; 2-rows-per-load; non-temporal streams) — all neutral-to-negative.
// Measured invariant: ~10G gathered rows/s across 5 gather implementations
// (fp32/bf16 x 1-wide/8-wide/2-row) => scattered-request saturation. This is
// the verified-best decomposition: de-fused pure gathers (max TLP), streaming
// dual GEMM, bf16 gate/energy arrays, XCD-partitioned CSR build.

#define N_NODES 50000
#define N_EDGES 800000
#define N_GRAPH 500
#define N_LAYERS 4
#define HDIM 64
#define DDIN 128
#define BN_EPS 1e-5f
#define NEPART 256
#define SC_CHUNK 2048
#define SC_NBLK ((N_NODES + SC_CHUNK - 1) / SC_CHUNK)  // 25
#define NPARTS 8
#define PRNG (N_NODES / NPARTS)  // 6250 exactly
#define FILL_BPP 56              // blocks per partition in partitioned kernels

typedef __hip_bfloat16 bf16;

// ---------------- CSR build ----------------

// XCD-partitioned degree count (verified r6).
__global__ __launch_bounds__(256) void k_degrees(const int* __restrict__ ei,
                                                 int* __restrict__ deg_in,
                                                 int* __restrict__ deg_out) {
  int part = blockIdx.x & (NPARTS - 1);
  int slice = blockIdx.x >> 3;
  int nslice = gridDim.x >> 3;
  int lo = part * PRNG, hi = lo + PRNG;
  int stride = nslice * 256;
  for (int e = slice * 256 + threadIdx.x; e < N_EDGES; e += stride) {
    int s = ei[e], d = ei[N_EDGES + e];
    if (s >= lo && s < hi) atomicAdd(&deg_out[s], 1);
    if (d >= lo && d < hi) atomicAdd(&deg_in[d], 1);
  }
}

// phase 1: per-block local exclusive scan (2048 elems) + block sums.
__global__ __launch_bounds__(256) void k_scan1(const int* __restrict__ deg_in,
                                               const int* __restrict__ deg_out,
                                               int* __restrict__ rp_dst,
                                               int* __restrict__ rp_src,
                                               int* __restrict__ bsum) {
  int arr = blockIdx.y;
  const int* in = arr ? deg_out : deg_in;
  int* out = arr ? rp_src : rp_dst;
  int base = blockIdx.x * SC_CHUNK + threadIdx.x * 8;
  int v[8];
  int s = 0;
#pragma unroll
  for (int j = 0; j < 8; ++j) {
    int ii = base + j;
    v[j] = (ii < N_NODES) ? in[ii] : 0;
    s += v[j];
  }
  __shared__ int sh[256];
  sh[threadIdx.x] = s;
  __syncthreads();
  for (int off = 1; off < 256; off <<= 1) {
    int t = (threadIdx.x >= off) ? sh[threadIdx.x - off] : 0;
    __syncthreads();
    sh[threadIdx.x] += t;
    __syncthreads();
  }
  int run = sh[threadIdx.x] - s;
#pragma unroll
  for (int j = 0; j < 8; ++j) {
    int ii = base + j;
    if (ii < N_NODES) out[ii] = run;
    run += v[j];
  }
  if (threadIdx.x == 255) bsum[arr * SC_NBLK + blockIdx.x] = sh[255];
}

// phase 2: scan the block sums (one wave), set rp[N]=E.
__global__ __launch_bounds__(64) void k_scan2(const int* __restrict__ bsum,
                                              int* __restrict__ boff,
                                              int* __restrict__ rp_dst,
                                              int* __restrict__ rp_src) {
  int lane = threadIdx.x;
  for (int a = 0; a < 2; ++a) {
    int v = (lane < SC_NBLK) ? bsum[a * SC_NBLK + lane] : 0;
    int incl = v;
    for (int off = 1; off < 64; off <<= 1) {
      int t = __shfl_up(incl, off);
      if (lane >= off) incl += t;
    }
    if (lane < SC_NBLK) boff[a * SC_NBLK + lane] = incl - v;
  }
  if (lane == 0) {
    rp_dst[N_NODES] = N_EDGES;
    rp_src[N_NODES] = N_EDGES;
  }
}

// phase 3: add block offsets, write cursor copies; fuse dinv (arr 0).
__global__ __launch_bounds__(256) void k_scan3(const int* __restrict__ boff,
                                               int* __restrict__ rp_dst,
                                               int* __restrict__ rp_src,
                                               int* __restrict__ cur_dst,
                                               int* __restrict__ cur_src,
                                               const int* __restrict__ deg_in,
                                               float* __restrict__ dinv) {
  int arr = blockIdx.y;
  int* rp = arr ? rp_src : rp_dst;
  int* cur = arr ? cur_src : cur_dst;
  int off = boff[arr * SC_NBLK + blockIdx.x];
  int base = blockIdx.x * SC_CHUNK + threadIdx.x * 8;
#pragma unroll
  for (int j = 0; j < 8; ++j) {
    int ii = base + j;
    if (ii < N_NODES) {
      int v = rp[ii] + off;
      rp[ii] = v;
      cur[ii] = v;
      if (arr == 0) dinv[ii] = rsqrtf((float)(deg_in[ii] + 1));  // + self loop
    }
  }
}

// XCD-partitioned fill (verified r6).
__global__ __launch_bounds__(256) void k_fill(const int* __restrict__ ei,
                                              int* __restrict__ cur_dst,
                                              int* __restrict__ cur_src,
                                              int* __restrict__ csr_dst,
                                              int* __restrict__ csr_src) {
  int part = blockIdx.x & (NPARTS - 1);
  int slice = blockIdx.x >> 3;
  int nslice = gridDim.x >> 3;
  int lo = part * PRNG, hi = lo + PRNG;
  int stride = nslice * 256;
  for (int e = slice * 256 + threadIdx.x; e < N_EDGES; e += stride) {
    int s = ei[e], d = ei[N_EDGES + e];
    if (d >= lo && d < hi) {
      int q = atomicAdd(&cur_dst[d], 1);
      csr_dst[q] = s;  // source node for dst-gather
    }
    if (s >= lo && s < hi) {
      int q = atomicAdd(&cur_src[s], 1);
      csr_src[q] = d;  // dest node for src-gather
    }
  }
}

// ---------------- dense kernels ----------------

__global__ __launch_bounds__(256) void k_prelin(const float* __restrict__ x0,
                                                const float* __restrict__ W,
                                                const float* __restrict__ b,
                                                float* __restrict__ x) {
  __shared__ float Ws[DDIN * HDIM];  // 32 KB
  for (int t = threadIdx.x; t < DDIN * HDIM; t += 256) Ws[t] = W[t];
  __syncthreads();
  int wave = threadIdx.x >> 6, lane = threadIdx.x & 63;
  float bias = b[lane];
  int stride = gridDim.x * 4;
  for (int i = blockIdx.x * 4 + wave; i < N_NODES; i += stride) {
    const float* xr = x0 + (size_t)i * DDIN;
    float xl0 = xr[lane], xl1 = xr[64 + lane];
    float acc = bias;
#pragma unroll
    for (int k = 0; k < 64; ++k) acc = fmaf(__shfl(xl0, k), Ws[k * 64 + lane], acc);
#pragma unroll
    for (int k = 0; k < 64; ++k) acc = fmaf(__shfl(xl1, k), Ws[(64 + k) * 64 + lane], acc);
    x[(size_t)i * HDIM + lane] = fmaxf(acc, 0.f);
  }
}

// ---------------- pure gather (one wave per node, r3-verified structure) -----
// aggb[i] = dinv[i] * (x[i]*dinv[i] + sum_{s in in(i)} x[s]*dinv[s])
__global__ __launch_bounds__(256) void k_agg(const float* __restrict__ x,
                                             const int* __restrict__ rp,
                                             const int* __restrict__ csr,
                                             const float* __restrict__ dinv,
                                             float* __restrict__ aggb) {
  int i = (blockIdx.x * 256 + threadIdx.x) >> 6;
  int lane = threadIdx.x & 63;
  if (i >= N_NODES) return;
  int e0 = rp[i], e1 = rp[i + 1];
  float di = dinv[i];
  size_t li = (size_t)i * HDIM + lane;
  float a0 = x[li] * di, a1 = 0.f, a2 = 0.f, a3 = 0.f;  // self loop in a0
  for (int base = e0; base < e1; base += 64) {
    int m = e1 - base;
    if (m > 64) m = 64;
    int idx = csr[base + (lane < m ? lane : 0)];
    float dv = dinv[idx];
    int k = 0;
    for (; k + 8 <= m; k += 8) {
      int s0 = __shfl(idx, k), s1 = __shfl(idx, k + 1), s2 = __shfl(idx, k + 2),
          s3 = __shfl(idx, k + 3), s4 = __shfl(idx, k + 4), s5 = __shfl(idx, k + 5),
          s6 = __shfl(idx, k + 6), s7 = __shfl(idx, k + 7);
      float w0 = __shfl(dv, k), w1 = __shfl(dv, k + 1), w2 = __shfl(dv, k + 2),
            w3 = __shfl(dv, k + 3), w4 = __shfl(dv, k + 4), w5 = __shfl(dv, k + 5),
            w6 = __shfl(dv, k + 6), w7 = __shfl(dv, k + 7);
      float v0 = x[(size_t)s0 * HDIM + lane], v1 = x[(size_t)s1 * HDIM + lane];
      float v2 = x[(size_t)s2 * HDIM + lane], v3 = x[(size_t)s3 * HDIM + lane];
      float v4 = x[(size_t)s4 * HDIM + lane], v5 = x[(size_t)s5 * HDIM + lane];
      float v6 = x[(size_t)s6 * HDIM + lane], v7 = x[(size_t)s7 * HDIM + lane];
      a0 = fmaf(v0, w0, a0);
      a1 = fmaf(v1, w1, a1);
      a2 = fmaf(v2, w2, a2);
      a3 = fmaf(v3, w3, a3);
      a0 = fmaf(v4, w4, a0);
      a1 = fmaf(v5, w5, a1);
      a2 = fmaf(v6, w6, a2);
      a3 = fmaf(v7, w7, a3);
    }
    for (; k < m; ++k) {
      int s = __shfl(idx, k);
      float w = __shfl(dv, k);
      a0 = fmaf(x[(size_t)s * HDIM + lane], w, a0);
    }
  }
  aggb[li] = (a0 + a1 + a2 + a3) * di;
}

// ---------------- streaming dual GEMM (r3-verified, bf16 Xch out) -----------
// x_ = relu(agg@W1+b1) [fp32], Xch = relu(agg@W2+b2) [bf16, gate input only].
__global__ __launch_bounds__(256) void k_gemm2(const float* __restrict__ agg,
                                               const float* __restrict__ W1,
                                               const float* __restrict__ W2,
                                               const float* __restrict__ b1,
                                               const float* __restrict__ b2,
                                               float* __restrict__ x_,
                                               bf16* __restrict__ Xch) {
  __shared__ float W1s[HDIM * HDIM], W2s[HDIM * HDIM];
  for (int t = threadIdx.x; t < HDIM * HDIM; t += 256) {
    W1s[t] = W1[t];
    W2s[t] = W2[t];
  }
  __syncthreads();
  int wave = threadIdx.x >> 6, lane = threadIdx.x & 63;
  float bb1 = b1[lane], bb2 = b2[lane];
  int stride = gridDim.x * 4;
  for (int i = blockIdx.x * 4 + wave; i < N_NODES; i += stride) {
    size_t li = (size_t)i * HDIM + lane;
    float xl = agg[li];
    float r1 = 0.f, r2 = 0.f;
#pragma unroll
    for (int k = 0; k < 64; ++k) {
      float xv = __shfl(xl, k);
      r1 = fmaf(xv, W1s[k * 64 + lane], r1);
      r2 = fmaf(xv, W2s[k * 64 + lane], r2);
    }
    x_[li] = fmaxf(r1 + bb1, 0.f);
    Xch[li] = __float2bfloat16(fmaxf(r2 + bb2, 0.f));
  }
}

// tau = tanh(mean_over_out_edges (Xc[i]-Xc[d])^2) on bf16 rows;
// x = (1-tau)*x + tau*x_ ; also emit bf16 copy of new x for the energy pass.
__global__ __launch_bounds__(256) void k_gate(const bf16* __restrict__ Xch,
                                              const float* __restrict__ x_,
                                              const int* __restrict__ rp,
                                              const int* __restrict__ csr,
                                              float* __restrict__ x,
                                              bf16* __restrict__ xh) {
  int i = (blockIdx.x * 256 + threadIdx.x) >> 6;
  int lane = threadIdx.x & 63;
  if (i >= N_NODES) return;
  int e0 = rp[i], e1 = rp[i + 1];
  float xi = __bfloat162float(Xch[(size_t)i * HDIM + lane]);
  float a0 = 0.f, a1 = 0.f, a2 = 0.f, a3 = 0.f;
  for (int base = e0; base < e1; base += 64) {
    int m = e1 - base;
    if (m > 64) m = 64;
    int idx = csr[base + (lane < m ? lane : 0)];
    int k = 0;
    for (; k + 8 <= m; k += 8) {
      int s0 = __shfl(idx, k), s1 = __shfl(idx, k + 1), s2 = __shfl(idx, k + 2),
          s3 = __shfl(idx, k + 3), s4 = __shfl(idx, k + 4), s5 = __shfl(idx, k + 5),
          s6 = __shfl(idx, k + 6), s7 = __shfl(idx, k + 7);
      float v0 = __bfloat162float(Xch[(size_t)s0 * HDIM + lane]);
      float v1 = __bfloat162float(Xch[(size_t)s1 * HDIM + lane]);
      float v2 = __bfloat162float(Xch[(size_t)s2 * HDIM + lane]);
      float v3 = __bfloat162float(Xch[(size_t)s3 * HDIM + lane]);
      float v4 = __bfloat162float(Xch[(size_t)s4 * HDIM + lane]);
      float v5 = __bfloat162float(Xch[(size_t)s5 * HDIM + lane]);
      float v6 = __bfloat162float(Xch[(size_t)s6 * HDIM + lane]);
      float v7 = __bfloat162float(Xch[(size_t)s7 * HDIM + lane]);
      float t0 = xi - v0, t1 = xi - v1, t2 = xi - v2, t3 = xi - v3;
      float t4 = xi - v4, t5 = xi - v5, t6 = xi - v6, t7 = xi - v7;
      a0 = fmaf(t0, t0, a0);
      a1 = fmaf(t1, t1, a1);
      a2 = fmaf(t2, t2, a2);
      a3 = fmaf(t3, t3, a3);
      a0 = fmaf(t4, t4, a0);
      a1 = fmaf(t5, t5, a1);
      a2 = fmaf(t6, t6, a2);
      a3 = fmaf(t7, t7, a3);
    }
    for (; k < m; ++k) {
      int d = __shfl(idx, k);
      float t = xi - __bfloat162float(Xch[(size_t)d * HDIM + lane]);
      a0 = fmaf(t, t, a0);
    }
  }
  int cnt = e1 - e0;
  float tau = tanhf((a0 + a1 + a2 + a3) / (float)(cnt > 0 ? cnt : 1));
  size_t idx = (size_t)i * HDIM + lane;
  float xn = (1.f - tau) * x[idx] + tau * x_[idx];
  x[idx] = xn;
  xh[idx] = __float2bfloat16(xn);
}

// energy partials (grouped by src, bf16 rows) + global add pool (fp32), fused.
__global__ __launch_bounds__(256) void k_epool(const float* __restrict__ x,
                                               const bf16* __restrict__ xh,
                                               const int* __restrict__ rp,
                                               const int* __restrict__ csr,
                                               const int* __restrict__ batch,
                                               float* __restrict__ hpool,
                                               float* __restrict__ epart) {
  int i = (blockIdx.x * 256 + threadIdx.x) >> 6;
  int lane = threadIdx.x & 63;
  if (i >= N_NODES) return;
  size_t li = (size_t)i * HDIM + lane;
  float xi = __bfloat162float(xh[li]);  // symmetric rounding vs gathered rows
  int e0 = rp[i], e1 = rp[i + 1];
  float a0 = 0.f, a1 = 0.f, a2 = 0.f, a3 = 0.f;
  for (int base = e0; base < e1; base += 64) {
    int m = e1 - base;
    if (m > 64) m = 64;
    int idx = csr[base + (lane < m ? lane : 0)];
    int k = 0;
    for (; k + 8 <= m; k += 8) {
      int s0 = __shfl(idx, k), s1 = __shfl(idx, k + 1), s2 = __shfl(idx, k + 2),
          s3 = __shfl(idx, k + 3), s4 = __shfl(idx, k + 4), s5 = __shfl(idx, k + 5),
          s6 = __shfl(idx, k + 6), s7 = __shfl(idx, k + 7);
      float v0 = __bfloat162float(xh[(size_t)s0 * HDIM + lane]);
      float v1 = __bfloat162float(xh[(size_t)s1 * HDIM + lane]);
      float v2 = __bfloat162float(xh[(size_t)s2 * HDIM + lane]);
      float v3 = __bfloat162float(xh[(size_t)s3 * HDIM + lane]);
      float v4 = __bfloat162float(xh[(size_t)s4 * HDIM + lane]);
      float v5 = __bfloat162float(xh[(size_t)s5 * HDIM + lane]);
      float v6 = __bfloat162float(xh[(size_t)s6 * HDIM + lane]);
      float v7 = __bfloat162float(xh[(size_t)s7 * HDIM + lane]);
      float t0 = xi - v0, t1 = xi - v1, t2 = xi - v2, t3 = xi - v3;
      float t4 = xi - v4, t5 = xi - v5, t6 = xi - v6, t7 = xi - v7;
      a0 = fmaf(t0, t0, a0);
      a1 = fmaf(t1, t1, a1);
      a2 = fmaf(t2, t2, a2);
      a3 = fmaf(t3, t3, a3);
      a0 = fmaf(t4, t4, a0);
      a1 = fmaf(t5, t5, a1);
      a2 = fmaf(t6, t6, a2);
      a3 = fmaf(t7, t7, a3);
    }
    for (; k < m; ++k) {
      int d = __shfl(idx, k);
      float t = xi - __bfloat162float(xh[(size_t)d * HDIM + lane]);
      a0 = fmaf(t, t, a0);
    }
  }
  int g = batch[i];  // wave-uniform
  atomicAdd(&hpool[g * HDIM + lane], x[li]);  // exact fp32 pool
  float acc = a0 + a1 + a2 + a3;
  acc += __shfl_down(acc, 32);
  acc += __shfl_down(acc, 16);
  acc += __shfl_down(acc, 8);
  acc += __shfl_down(acc, 4);
  acc += __shfl_down(acc, 2);
  acc += __shfl_down(acc, 1);
  if (lane == 0) atomicAdd(&epart[i & (NEPART - 1)], acc);
}

__global__ __launch_bounds__(256) void k_esum(const float* __restrict__ epart,
                                              float* __restrict__ out_e) {
  __shared__ float sh[NEPART];
  int t = threadIdx.x;
  sh[t] = epart[t];
  __syncthreads();
  for (int off = NEPART / 2; off > 0; off >>= 1) {
    if (t < off) sh[t] += sh[t + off];
    __syncthreads();
  }
  if (t == 0) out_e[0] = 0.5f * sh[0];
}

// ---------------- readout MLP (fused GEMM + BN + relu, one block per column) --

__global__ __launch_bounds__(256) void k_mlpbn(const float* __restrict__ Hin,
                                               const float* __restrict__ W,
                                               const float* __restrict__ b,
                                               const float* __restrict__ g,
                                               const float* __restrict__ bb,
                                               float* __restrict__ Z) {
  int c = blockIdx.x;
  __shared__ float Wc[HDIM];
  __shared__ float red[256];
  if (threadIdx.x < HDIM) Wc[threadIdx.x] = W[threadIdx.x * HDIM + c];
  __syncthreads();
  int r0 = threadIdx.x, r1 = threadIdx.x + 256;
  float bc = b[c];
  float d0 = bc, d1 = bc;
  if (r0 < N_GRAPH) {
    const float* h = Hin + (size_t)r0 * HDIM;
#pragma unroll
    for (int k = 0; k < HDIM; ++k) d0 = fmaf(h[k], Wc[k], d0);
  }
  if (r1 < N_GRAPH) {
    const float* h = Hin + (size_t)r1 * HDIM;
#pragma unroll
    for (int k = 0; k < HDIM; ++k) d1 = fmaf(h[k], Wc[k], d1);
  }
  red[threadIdx.x] = (r0 < N_GRAPH ? d0 : 0.f) + (r1 < N_GRAPH ? d1 : 0.f);
  __syncthreads();
  for (int off = 128; off > 0; off >>= 1) {
    if (threadIdx.x < off) red[threadIdx.x] += red[threadIdx.x + off];
    __syncthreads();
  }
  float mean = red[0] / (float)N_GRAPH;
  __syncthreads();
  float t0 = (r0 < N_GRAPH) ? d0 - mean : 0.f;
  float t1 = (r1 < N_GRAPH) ? d1 - mean : 0.f;
  red[threadIdx.x] = t0 * t0 + t1 * t1;
  __syncthreads();
  for (int off = 128; off > 0; off >>= 1) {
    if (threadIdx.x < off) red[threadIdx.x] += red[threadIdx.x + off];
    __syncthreads();
  }
  float var = red[0] / (float)N_GRAPH;
  float scale = rsqrtf(var + BN_EPS) * g[c];
  float bias = bb[c];
  if (r0 < N_GRAPH) Z[(size_t)r0 * HDIM + c] = fmaxf(fmaf(t0, scale, bias), 0.f);
  if (r1 < N_GRAPH) Z[(size_t)r1 * HDIM + c] = fmaxf(fmaf(t1, scale, bias), 0.f);
}

__global__ __launch_bounds__(256) void k_final(const float* __restrict__ H,
                                               const float* __restrict__ w,
                                               const float* __restrict__ b,
                                               float* __restrict__ out) {
  int r = blockIdx.x * 256 + threadIdx.x;
  if (r >= N_GRAPH) return;
  float acc = b[0];
#pragma unroll
  for (int k = 0; k < 64; ++k) acc = fmaf(H[r * HDIM + k], w[k], acc);
  out[r] = acc;
  out[N_GRAPH + r] = acc;
}

// ---------------- launch ----------------

extern "C" void kernel_launch(void* const* d_in, const int* in_sizes, int n_in,
                              void* d_out, int out_size, void* d_ws, size_t ws_size,
                              hipStream_t stream) {
  (void)in_sizes; (void)n_in; (void)out_size; (void)ws_size;
  const float* x0    = (const float*)d_in[0];
  const int*   ei    = (const int*)d_in[1];
  const int*   batch = (const int*)d_in[2];
  const float* preW  = (const float*)d_in[3];
  const float* preb  = (const float*)d_in[4];
  const float* convW = (const float*)d_in[5];
  const float* convb = (const float*)d_in[6];
  const float* ggW   = (const float*)d_in[7];
  const float* ggb   = (const float*)d_in[8];
  const float* lin1W = (const float*)d_in[9];
  const float* lin1b = (const float*)d_in[10];
  const float* lin2W = (const float*)d_in[11];
  const float* lin2b = (const float*)d_in[12];
  const float* lin3W = (const float*)d_in[13];
  const float* lin3b = (const float*)d_in[14];
  const float* lin4W = (const float*)d_in[15];
  const float* lin4b = (const float*)d_in[16];
  const float* bng   = (const float*)d_in[17];
  const float* bnb   = (const float*)d_in[18];
  float* out = (float*)d_out;

  char* ws = (char*)d_ws;
  size_t off = 0;
  auto alloc = [&](size_t bytes) -> void* {
    off = (off + 255) & ~(size_t)255;
    void* p = ws + off;
    off += bytes;
    return p;
  };
  int* deg_in   = (int*)alloc(2ull * N_NODES * 4);  // deg_in, deg_out (memset)
  int* deg_out  = deg_in + N_NODES;
  int* rp_dst   = (int*)alloc((N_NODES + 1) * 4);
  int* rp_src   = (int*)alloc((N_NODES + 1) * 4);
  int* cur_dst  = (int*)alloc((N_NODES + 1) * 4);
  int* cur_src  = (int*)alloc((N_NODES + 1) * 4);
  int* bsum     = (int*)alloc(2 * SC_NBLK * 4);
  int* boff     = (int*)alloc(2 * SC_NBLK * 4);
  int* csr_dst  = (int*)alloc((size_t)N_EDGES * 4);
  int* csr_src  = (int*)alloc((size_t)N_EDGES * 4);
  float* dinv   = (float*)alloc(N_NODES * 4);
  float* x      = (float*)alloc((size_t)N_NODES * HDIM * 4);
  float* aggb   = (float*)alloc((size_t)N_NODES * HDIM * 4);
  float* x_     = (float*)alloc((size_t)N_NODES * HDIM * 4);
  bf16* Xch     = (bf16*)alloc((size_t)N_NODES * HDIM * 2);
  bf16* xh      = (bf16*)alloc((size_t)N_NODES * HDIM * 2);
  float* hpool  = (float*)alloc(N_GRAPH * HDIM * 4);
  float* epart  = (float*)alloc(NEPART * 4);
  float* mlpA   = (float*)alloc(N_GRAPH * HDIM * 4);
  float* mlpB   = (float*)alloc(N_GRAPH * HDIM * 4);

  hipMemsetAsync(deg_in, 0, 2ull * N_NODES * 4, stream);
  hipMemsetAsync(hpool, 0, N_GRAPH * HDIM * 4, stream);
  hipMemsetAsync(epart, 0, NEPART * 4, stream);

  k_degrees<<<NPARTS * FILL_BPP, 256, 0, stream>>>(ei, deg_in, deg_out);
  {
    dim3 g(SC_NBLK, 2);
    k_scan1<<<g, 256, 0, stream>>>(deg_in, deg_out, rp_dst, rp_src, bsum);
    k_scan2<<<1, 64, 0, stream>>>(bsum, boff, rp_dst, rp_src);
    k_scan3<<<g, 256, 0, stream>>>(boff, rp_dst, rp_src, cur_dst, cur_src, deg_in, dinv);
  }
  k_fill<<<NPARTS * FILL_BPP, 256, 0, stream>>>(ei, cur_dst, cur_src, csr_dst, csr_src);

  k_prelin<<<512, 256, 0, stream>>>(x0, preW, preb, x);

  const int gnode = (N_NODES + 3) / 4;
  for (int l = 0; l < N_LAYERS; ++l) {
    k_agg<<<gnode, 256, 0, stream>>>(x, rp_dst, csr_dst, dinv, aggb);
    k_gemm2<<<1024, 256, 0, stream>>>(aggb, convW + l * HDIM * HDIM, ggW + l * HDIM * HDIM,
                                      convb + l * HDIM, ggb + l * HDIM, x_, Xch);
    k_gate<<<gnode, 256, 0, stream>>>(Xch, x_, rp_src, csr_src, x, xh);
  }

  k_epool<<<gnode, 256, 0, stream>>>(x, xh, rp_src, csr_src, batch, hpool, epart);
  k_esum<<<1, NEPART, 0, stream>>>(epart, out + 2 * N_GRAPH);

  k_mlpbn<<<HDIM, 256, 0, stream>>>(hpool, lin1W, lin1b, bng, bnb, mlpA);
  k_mlpbn<<<HDIM, 256, 0, stream>>>(mlpA, lin2W, lin2b, bng, bnb, mlpB);
  k_mlpbn<<<HDIM, 256, 0, stream>>>(mlpB, lin3W, lin3b, bng, bnb, mlpA);
  k_final<<<(N_GRAPH + 255) / 256, 256, 0, stream>>>(mlpA, lin4W, lin4b, out);
}